// Round 25
// baseline (53.139 us; speedup 1.0000x reference)
//
#include <hip/hip_runtime.h>

#define N_REAL 12
#define BATCH  4
#define CH     3
#define HH     256
#define WW     256
#define KK     4
#define TY     8                  // output rows per block (8 waves x 1 row)
#define ROWST  11                 // TY + KK - 1 input rows
#define RSTR   256                // packed LDS row stride (dwords)
#define NTHR   512
#define HW     (HH * WW)
#define BUFSZ  (ROWST * RSTR)     // 2816 dwords per buffer

typedef float f32x4 __attribute__((ext_vector_type(4)));
typedef __attribute__((address_space(1))) const void gas_t;
typedef __attribute__((address_space(3))) void las_t;

// async global->LDS DMA: wave-uniform LDS base + lane*16B; one 256-dword row.
#define ASYNC_ROW16(gsrc, ldst) \
    __builtin_amdgcn_global_load_lds((gas_t*)(gsrc), (las_t*)(ldst), 16, 0, 0)

__device__ __forceinline__ float sigmoidf(float x) {
    float e = __builtin_amdgcn_exp2f(x * -1.44269504088896340736f);
    return __builtin_amdgcn_rcpf(1.0f + e);
}

// DPP wave shifts: bound_ctrl=1 -> out-of-wave lanes read 0 = image-edge pad.
__device__ __forceinline__ float dpp_shr1(float x) {   // lane i <- lane i-1
    return __int_as_float(__builtin_amdgcn_update_dpp(
        0, __float_as_int(x), 0x138 /*wave_shr:1*/, 0xf, 0xf, true));
}
__device__ __forceinline__ float dpp_shl1(float x) {   // lane i <- lane i+1
    return __int_as_float(__builtin_amdgcn_update_dpp(
        0, __float_as_int(x), 0x130 /*wave_shl:1*/, 0xf, 0xf, true));
}

__global__ __launch_bounds__(NTHR, 8)   // 8 waves/EU target: 32 waves/CU, VGPR cap 64
void reverb_fused(const float* __restrict__ states,
                  const float* __restrict__ weights,
                  const float* __restrict__ bias,
                  float*       __restrict__ out)
{
    __shared__ __align__(16) float S[2][BUFSZ];   // 22.5 KB -> occupancy wave-capped

    const int ty  = blockIdx.x;            // 0..31
    const int b   = blockIdx.y;            // batch
    const int v   = blockIdx.z;            // dest node
    const int tid = threadIdx.x;
    const int w   = tid >> 6;              // wave 0..7: owns output row gy0+w
    const int ln  = tid & 63;              // lane: owns cols 4ln..4ln+3
    const int gy0 = ty * TY;
    const int deg = (v == 0) ? 4 : 3;
    const int P   = 3 * deg;               // (edge,channel) phases

    // ---- staging metadata: wave w DMAs rows w and (w<3) 8+w  (r < 11) ----
    int  rr[2], goff[2];
    bool rvalid[2], rowok[2];
    #pragma unroll
    for (int k = 0; k < 2; ++k) {
        const int r = w + 8 * k;
        rr[k]     = r;
        rvalid[k] = (r < ROWST);           // wave-uniform
        const int gy  = gy0 + r - 1;       // SAME pad lo=1
        const int gyc = gy < 0 ? 0 : (gy > HH - 1 ? HH - 1 : gy);
        goff[k]  = gyc * WW + 4 * ln;
        rowok[k] = (unsigned)gy < (unsigned)HH;
    }

    // ---- consume metadata: wave w reads rows w+lr (gy = gy0+w-1+lr) ----
    bool crowok[KK];
    #pragma unroll
    for (int lr = 0; lr < KK; ++lr)
        crowok[lr] = (unsigned)(gy0 + w - 1 + lr) < (unsigned)HH;  // wave-uniform

    // ---- edge tables (uniform) ----
    int ucA[4], eA[4];
    #pragma unroll
    for (int ei = 0; ei < 4; ++ei) {
        int t = v + 11 - ei; if (t >= 12) t -= 12;
        ucA[ei] = (ei == 3) ? 12 : t;
        eA[ei]  = (ei == 3) ? 36 : (ucA[ei] * 3 + ei);
    }

    float bsum[CH] = {0.f, 0.f, 0.f};
    for (int ei = 0; ei < deg; ++ei) {
        bsum[0] += bias[eA[ei] * CH + 0];
        bsum[1] += bias[eA[ei] * CH + 1];
        bsum[2] += bias[eA[ei] * CH + 2];
    }

    float acc[CH][4];                      // 12 accumulators (1 row x 4 px x 3 co)
    #pragma unroll
    for (int co = 0; co < CH; ++co)
        #pragma unroll
        for (int p = 0; p < 4; ++p) acc[co][p] = 0.0f;

    // ---- prologue: DMA phase 0 into S[0], wait, sigmoid in place ----
    {
        const float* srcC0 = states + (size_t)(ucA[0] * BATCH + b) * CH * HW; // ci=0
        #pragma unroll
        for (int k = 0; k < 2; ++k)
            if (rvalid[k])
                ASYNC_ROW16(srcC0 + goff[k], &S[0][rr[k] * RSTR]);
        asm volatile("s_waitcnt vmcnt(0)" ::: "memory");
        __builtin_amdgcn_sched_barrier(0);
        #pragma unroll
        for (int k = 0; k < 2; ++k) {
            if (rvalid[k]) {
                float* rp = &S[0][rr[k] * RSTR + 4 * ln];
                const f32x4 q = *(const f32x4*)rp;
                f32x4 t;
                if (rowok[k]) {
                    t.x = sigmoidf(q.x); t.y = sigmoidf(q.y);
                    t.z = sigmoidf(q.z); t.w = sigmoidf(q.w);
                } else t = (f32x4){0.f, 0.f, 0.f, 0.f};
                *(f32x4*)rp = t;
            }
        }
    }
    __syncthreads();

    for (int p = 0; p < P; ++p) {
        const int cur  = p & 1;
        const bool more = (p + 1 < P);

        // ---- issue next phase's DMA into the freed buffer (zero VGPR cost) ----
        if (more) {
            const int p1  = p + 1;
            const int ei1 = p1 / 3;
            const int ci1 = p1 - 3 * ei1;
            const float* srcC1 = states +
                (size_t)(ucA[ei1] * BATCH + b) * CH * HW + (size_t)ci1 * HW;
            #pragma unroll
            for (int k = 0; k < 2; ++k)
                if (rvalid[k])
                    ASYNC_ROW16(srcC1 + goff[k], &S[cur ^ 1][rr[k] * RSTR]);
        }

        // ---- compute phase p: 4 rows, ky = lr (compile-time), DPP halo ----
        {
            const int ei = p / 3;
            const int ci = p - 3 * ei;
            const float* __restrict__ wbase = weights + eA[ei] * (CH * CH * KK * KK);
            #pragma unroll
            for (int lr = 0; lr < KK; ++lr) {
                if (!crowok[lr]) continue;            // wave-uniform (y pad -> 0)
                const float* rp = &S[cur][(w + lr) * RSTR + 4 * ln];
                const f32x4 Bq = *(const f32x4*)rp;   // sigmoided
                const float vv[7] = {dpp_shr1(Bq.w),  // x-1 (lane0 -> 0)
                                     Bq.x, Bq.y, Bq.z, Bq.w,
                                     dpp_shl1(Bq.x),  // x+4 (lane63 -> 0)
                                     dpp_shl1(Bq.y)}; // x+5 (lane63 -> 0)
                #pragma unroll
                for (int co = 0; co < CH; ++co) {
                    const f32x4 wv =
                        *(const f32x4*)(wbase + ((co * CH + ci) * KK + lr) * KK);
                    #pragma unroll
                    for (int pp = 0; pp < 4; ++pp) {
                        acc[co][pp] = fmaf(wv.x, vv[pp + 0], acc[co][pp]);
                        acc[co][pp] = fmaf(wv.y, vv[pp + 1], acc[co][pp]);
                        acc[co][pp] = fmaf(wv.z, vv[pp + 2], acc[co][pp]);
                        acc[co][pp] = fmaf(wv.w, vv[pp + 3], acc[co][pp]);
                    }
                }
            }
        }

        // ---- wave-local: wait own DMA, sigmoid next tile in place ----
        if (more) {
            asm volatile("s_waitcnt vmcnt(0)" ::: "memory");
            __builtin_amdgcn_sched_barrier(0);
            #pragma unroll
            for (int k = 0; k < 2; ++k) {
                if (rvalid[k]) {
                    float* rp = &S[cur ^ 1][rr[k] * RSTR + 4 * ln];
                    const f32x4 q = *(const f32x4*)rp;
                    f32x4 t;
                    if (rowok[k]) {
                        t.x = sigmoidf(q.x); t.y = sigmoidf(q.y);
                        t.z = sigmoidf(q.z); t.w = sigmoidf(q.w);
                    } else t = (f32x4){0.f, 0.f, 0.f, 0.f};
                    *(f32x4*)rp = t;
                }
            }
            __syncthreads();               // single barrier per phase
        }
    }

    const float inv = 1.0f / (float)deg;
    const size_t obase = (size_t)(v * BATCH + b) * CH * HW;
    const int oy = gy0 + w;
    #pragma unroll
    for (int co = 0; co < CH; ++co) {
        f32x4 o;
        o.x = (acc[co][0] + bsum[co]) * inv;
        o.y = (acc[co][1] + bsum[co]) * inv;
        o.z = (acc[co][2] + bsum[co]) * inv;
        o.w = (acc[co][3] + bsum[co]) * inv;
        __builtin_nontemporal_store(o,
            (f32x4*)&out[obase + (size_t)co * HW + (size_t)oy * WW + 4 * ln]);
    }
}

extern "C" void kernel_launch(void* const* d_in, const int* in_sizes, int n_in,
                              void* d_out, int out_size, void* d_ws, size_t ws_size,
                              hipStream_t stream)
{
    const float* states  = (const float*)d_in[0];
    const float* weights = (const float*)d_in[1];
    const float* bias    = (const float*)d_in[2];
    float*       out     = (float*)d_out;

    dim3 grid(HH / TY, BATCH, N_REAL);     // 32 x 4 x 12 = 1536 blocks, 4/CU resident
    reverb_fused<<<grid, NTHR, 0, stream>>>(states, weights, bias, out);
}

// Round 26
// 47.401 us; speedup vs baseline: 1.1211x; 1.1211x over previous
//
#include <hip/hip_runtime.h>

#define N_REAL 12
#define BATCH  4
#define CH     3
#define HH     256
#define WW     256
#define KK     4
#define TY     16                 // output rows per block (8 waves x 2 rows)
#define ROWST  19                 // TY + KK - 1 input rows
#define RSTR   260                // packed LDS row stride (dwords): 256 data + 4 zero pad
#define NTHR   512
#define HW     (HH * WW)
#define BUFSZ  (4 + ROWST * RSTR) // guard quad + rows = 4944 dwords
#define NPAD   (4 + ROWST * 4)    // guard + per-row pads = 80 dwords per buffer

typedef float f32x4 __attribute__((ext_vector_type(4)));
typedef float f32x2 __attribute__((ext_vector_type(2)));
typedef __attribute__((address_space(1))) const void gas_t;
typedef __attribute__((address_space(3))) void las_t;

// async global->LDS DMA: wave-uniform LDS base + lane*16B; one 256-dword row.
#define ASYNC_ROW16(gsrc, ldst) \
    __builtin_amdgcn_global_load_lds((gas_t*)(gsrc), (las_t*)(ldst), 16, 0, 0)

__device__ __forceinline__ float sigmoidf(float x) {
    float e = __builtin_amdgcn_exp2f(x * -1.44269504088896340736f);
    return __builtin_amdgcn_rcpf(1.0f + e);
}

__global__ __launch_bounds__(NTHR, 4)
void reverb_fused(const float* __restrict__ states,
                  const float* __restrict__ weights,
                  const float* __restrict__ bias,
                  float*       __restrict__ out)
{
    __shared__ __align__(16) float S[2][BUFSZ];   // 38.6 KB

    const int ty  = blockIdx.x;            // 0..15
    const int b   = blockIdx.y;            // batch
    const int v   = blockIdx.z;            // dest node
    const int tid = threadIdx.x;
    const int w   = tid >> 6;              // wave 0..7: owns output rows gy0+2w, 2w+1
    const int ln  = tid & 63;              // lane: owns cols 4ln..4ln+3
    const int gy0 = ty * TY;
    const int deg = (v == 0) ? 4 : 3;
    const int P   = 3 * deg;               // (edge,channel) phases

    // ---- one-time zero of guard + row pads in BOTH buffers ----
    if (tid < 2 * NPAD) {
        const int bi = (tid >= NPAD) ? 1 : 0;
        const int j  = tid - bi * NPAD;
        if (j < 4) S[bi][j] = 0.0f;
        else {
            const int i = j - 4;
            S[bi][4 + (i >> 2) * RSTR + 256 + (i & 3)] = 0.0f;
        }
    }

    // ---- staging metadata: wave w owns rows w, w+8, w+16 (r < 19) ----
    int  rr[3], goff[3];
    bool rvalid[3], rowok[3];
    #pragma unroll
    for (int k = 0; k < 3; ++k) {
        const int r = w + 8 * k;
        rr[k]     = r;
        rvalid[k] = (r < ROWST);           // wave-uniform (false only w>2,k=2)
        const int gy  = gy0 + r - 1;       // SAME pad lo=1
        const int gyc = gy < 0 ? 0 : (gy > HH - 1 ? HH - 1 : gy);
        goff[k]  = gyc * WW + 4 * ln;
        rowok[k] = (unsigned)gy < (unsigned)HH;
    }

    // ---- edge tables (uniform) ----
    int ucA[4], eA[4];
    #pragma unroll
    for (int ei = 0; ei < 4; ++ei) {
        int t = v + 11 - ei; if (t >= 12) t -= 12;
        ucA[ei] = (ei == 3) ? 12 : t;
        eA[ei]  = (ei == 3) ? 36 : (ucA[ei] * 3 + ei);
    }

    float bsum[CH] = {0.f, 0.f, 0.f};
    for (int ei = 0; ei < deg; ++ei) {
        bsum[0] += bias[eA[ei] * CH + 0];
        bsum[1] += bias[eA[ei] * CH + 1];
        bsum[2] += bias[eA[ei] * CH + 2];
    }

    float acc[CH][2][4];
    #pragma unroll
    for (int co = 0; co < CH; ++co)
        #pragma unroll
        for (int yy = 0; yy < 2; ++yy)
            #pragma unroll
            for (int p = 0; p < 4; ++p) acc[co][yy][p] = 0.0f;

    // ---- prologue: DMA phase 0 into S[0], wait, sigmoid in place ----
    {
        const float* srcC0 = states + (size_t)(ucA[0] * BATCH + b) * CH * HW; // ci=0
        #pragma unroll
        for (int k = 0; k < 3; ++k)
            if (rvalid[k])
                ASYNC_ROW16(srcC0 + goff[k], &S[0][4 + rr[k] * RSTR]);
        asm volatile("s_waitcnt vmcnt(0)" ::: "memory");
        __builtin_amdgcn_sched_barrier(0);
        #pragma unroll
        for (int k = 0; k < 3; ++k) {
            if (rvalid[k]) {
                float* rp = &S[0][4 + rr[k] * RSTR + 4 * ln];
                const f32x4 q = *(const f32x4*)rp;
                f32x4 t;
                if (rowok[k]) {
                    t.x = sigmoidf(q.x); t.y = sigmoidf(q.y);
                    t.z = sigmoidf(q.z); t.w = sigmoidf(q.w);
                } else t = (f32x4){0.f, 0.f, 0.f, 0.f};
                *(f32x4*)rp = t;
            }
        }
    }
    __syncthreads();

    for (int p = 0; p < P; ++p) {
        const int cur  = p & 1;
        const bool more = (p + 1 < P);

        // ---- issue next phase's DMA into the freed buffer (zero VGPR cost) ----
        if (more) {
            const int p1  = p + 1;
            const int ei1 = p1 / 3;
            const int ci1 = p1 - 3 * ei1;
            const float* srcC1 = states +
                (size_t)(ucA[ei1] * BATCH + b) * CH * HW + (size_t)ci1 * HW;
            #pragma unroll
            for (int k = 0; k < 3; ++k)
                if (rvalid[k])
                    ASYNC_ROW16(srcC1 + goff[k], &S[cur ^ 1][4 + rr[k] * RSTR]);
        }

        // ---- compute phase p from S[cur] (covers the DMA latency) ----
        {
            const int ei = p / 3;
            const int ci = p - 3 * ei;
            const float* __restrict__ wbase = weights + eA[ei] * (CH * CH * KK * KK);
            #pragma unroll
            for (int lr = 0; lr < 5; ++lr) {
                const float* rp = &S[cur][4 + (2 * w + lr) * RSTR + 4 * ln];
                const f32x4 A  = *(const f32x4*)(rp - 4);   // A.w = x-1 (guard/pad)
                const f32x4 Bq = *(const f32x4*)(rp);
                const f32x2 Cq = *(const f32x2*)(rp + 4);   // x+4, x+5 (pad at edge)
                const float vv[7] = {A.w, Bq.x, Bq.y, Bq.z, Bq.w, Cq.x, Cq.y};
                #pragma unroll
                for (int yy = 0; yy < 2; ++yy) {
                    const int ky = lr - yy;
                    if (ky < 0 || ky > 3) continue;
                    #pragma unroll
                    for (int co = 0; co < CH; ++co) {
                        const f32x4 wv =
                            *(const f32x4*)(wbase + ((co * CH + ci) * KK + ky) * KK);
                        #pragma unroll
                        for (int pp = 0; pp < 4; ++pp) {
                            acc[co][yy][pp] = fmaf(wv.x, vv[pp + 0], acc[co][yy][pp]);
                            acc[co][yy][pp] = fmaf(wv.y, vv[pp + 1], acc[co][yy][pp]);
                            acc[co][yy][pp] = fmaf(wv.z, vv[pp + 2], acc[co][yy][pp]);
                            acc[co][yy][pp] = fmaf(wv.w, vv[pp + 3], acc[co][yy][pp]);
                        }
                    }
                }
            }
        }

        // ---- wave-local: wait own DMA, sigmoid next tile in place ----
        if (more) {
            asm volatile("s_waitcnt vmcnt(0)" ::: "memory");
            __builtin_amdgcn_sched_barrier(0);
            #pragma unroll
            for (int k = 0; k < 3; ++k) {
                if (rvalid[k]) {
                    float* rp = &S[cur ^ 1][4 + rr[k] * RSTR + 4 * ln];
                    const f32x4 q = *(const f32x4*)rp;
                    f32x4 t;
                    if (rowok[k]) {
                        t.x = sigmoidf(q.x); t.y = sigmoidf(q.y);
                        t.z = sigmoidf(q.z); t.w = sigmoidf(q.w);
                    } else t = (f32x4){0.f, 0.f, 0.f, 0.f};
                    *(f32x4*)rp = t;
                }
            }
            __syncthreads();               // single barrier per phase
        }
    }

    const float inv = 1.0f / (float)deg;
    const size_t obase = (size_t)(v * BATCH + b) * CH * HW;
    #pragma unroll
    for (int co = 0; co < CH; ++co) {
        #pragma unroll
        for (int yy = 0; yy < 2; ++yy) {
            const int oy = gy0 + 2 * w + yy;
            f32x4 o;
            o.x = (acc[co][yy][0] + bsum[co]) * inv;
            o.y = (acc[co][yy][1] + bsum[co]) * inv;
            o.z = (acc[co][yy][2] + bsum[co]) * inv;
            o.w = (acc[co][yy][3] + bsum[co]) * inv;
            __builtin_nontemporal_store(o,
                (f32x4*)&out[obase + (size_t)co * HW + (size_t)oy * WW + 4 * ln]);
        }
    }
}

extern "C" void kernel_launch(void* const* d_in, const int* in_sizes, int n_in,
                              void* d_out, int out_size, void* d_ws, size_t ws_size,
                              hipStream_t stream)
{
    const float* states  = (const float*)d_in[0];
    const float* weights = (const float*)d_in[1];
    const float* bias    = (const float*)d_in[2];
    float*       out     = (float*)d_out;

    dim3 grid(HH / TY, BATCH, N_REAL);     // 16 x 4 x 12 = 768 blocks = 3/CU resident
    reverb_fused<<<grid, NTHR, 0, stream>>>(states, weights, bias, out);
}